// Round 1
// baseline (387.054 us; speedup 1.0000x reference)
//
#include <hip/hip_runtime.h>

// GraphConv x3 on MI355X. R9: wave-autonomous layer blocks + once-built
// per-node edge lists. fillb bins edges node-major (ushort src, N<65536) so
// the per-layer bin phase (2 dependent global rounds + LDS atomic storm +
// 3 barriers) is GONE. Each wave owns 16 nodes end-to-end: coalesced 2KB
// list stage -> 4-node simultaneous gather (8 row-loads in flight over 256
// edges/wave) -> in-wave shfl reduce -> per-wave LDS A-tile -> 64 MFMAs ->
// epilogue. Zero __syncthreads; whole grid (782 blocks) co-resident.

#define C128 128
#define CAPN 64     // records per node; mean deg 16, Poisson tail ~1e-18

typedef short s16x8 __attribute__((ext_vector_type(8)));
typedef float f32x4 __attribute__((ext_vector_type(4)));

__device__ __forceinline__ ushort f2bf(float f) {        // RNE fp32->bf16
  unsigned u = __builtin_bit_cast(unsigned, f);
  u = (u + 0x7FFFu + ((u >> 16) & 1u)) >> 16;
  return (ushort)u;
}
__device__ __forceinline__ float bflo(unsigned v) {
  return __builtin_bit_cast(float, v << 16);
}
__device__ __forceinline__ float bfhi(unsigned v) {
  return __builtin_bit_cast(float, v & 0xFFFF0000u);
}
__device__ __forceinline__ unsigned pack2(float lo, float hi) {
  return (unsigned)f2bf(lo) | ((unsigned)f2bf(hi) << 16);
}

// ---------------------------------------------------------------------------
// prep: detect dtypes (wave-parallel ballot, not serial walk), zero per-node
// counters, pack 6 weight mats into MFMA fragment order. Wpack idx =
// (c*8+nt)*512 + lane*8 + j -> W[o=nt*16+(lane&15)][k=(c&3)*32+(lane>>4)*8+j];
// c<4 Wrel, c>=4 Wroot.
// ---------------------------------------------------------------------------
__global__ __launch_bounds__(256) void prep_kernel(const float* __restrict__ Wr0,
                                                   const float* __restrict__ Wt0,
                                                   const float* __restrict__ Wr1,
                                                   const float* __restrict__ Wt1,
                                                   const float* __restrict__ Wr2,
                                                   const float* __restrict__ Wt2,
                                                   ushort* __restrict__ Wpack,
                                                   const int* __restrict__ eidx,
                                                   const int* __restrict__ mask,
                                                   int* __restrict__ flags,
                                                   int* __restrict__ ncnt,
                                                   int nCnt) {
  int t = blockIdx.x * 256 + threadIdx.x;
  if (blockIdx.x == 0 && threadIdx.x < 64) {
    int i = threadIdx.x;
    unsigned long long be = __ballot(eidx[2 * i + 1] != 0);
    unsigned long long bm = __ballot((unsigned)mask[i] > 1u);
    if (i == 0) {
      flags[0] = (be == 0ull);   // 1 = edges are int64
      flags[1] = (bm == 0ull);   // 1 = masks are int32
    }
  }
  if (t < nCnt) ncnt[t] = 0;
  if (t < 3 * 32768) {
    int L = t >> 15;
    int r = t & 32767;
    int c = r >> 12;
    int nt = (r >> 9) & 7;
    int lane = (r >> 3) & 63;
    int j = r & 7;
    int o = nt * 16 + (lane & 15);
    int k = (c & 3) * 32 + (lane >> 4) * 8 + j;
    const float* src;
    if (L == 0)      src = (c < 4) ? Wr0 : Wt0;
    else if (L == 1) src = (c < 4) ? Wr1 : Wt1;
    else             src = (c < 4) ? Wr2 : Wt2;
    Wpack[t] = f2bf(src[o * C128 + k]);
  }
}

// ---------------------------------------------------------------------------
// fillb: edge -> per-node list, node-major. Counter line-padded (x16 ints).
// ---------------------------------------------------------------------------
__global__ __launch_bounds__(256) void fillb_kernel(const int* __restrict__ eidx,
                                                    const int* __restrict__ flags,
                                                    int* __restrict__ ncnt,
                                                    ushort* __restrict__ nlist,
                                                    int E) {
  int e = blockIdx.x * 256 + threadIdx.x;
  if (e >= E) return;
  int src, dst;
  if (flags[0]) { src = eidx[2 * e]; dst = eidx[2 * E + 2 * e]; }
  else          { src = eidx[e];     dst = eidx[E + e]; }
  int pos = atomicAdd(&ncnt[dst * 16], 1);
  if (pos < CAPN) nlist[(size_t)dst * CAPN + pos] = (ushort)src;
}

// ---------------------------------------------------------------------------
// Input dropout: fp32 x -> bf16 hd
// ---------------------------------------------------------------------------
__global__ __launch_bounds__(256) void drop_in_kernel(const float* __restrict__ x,
                                                      const void* __restrict__ mask,
                                                      const int* __restrict__ flags,
                                                      ushort* __restrict__ out, int n4) {
  int i = blockIdx.x * 256 + threadIdx.x;
  if (i >= n4) return;
  float4 v = ((const float4*)x)[i];
  int k0, k1, k2, k3;
  if (flags[1]) {
    int4 m = ((const int4*)mask)[i];
    k0 = m.x; k1 = m.y; k2 = m.z; k3 = m.w;
  } else {
    uchar4 m = ((const uchar4*)mask)[i];
    k0 = m.x; k1 = m.y; k2 = m.z; k3 = m.w;
  }
  ushort4 r;
  r.x = k0 ? f2bf(v.x * 2.5f) : (ushort)0;
  r.y = k1 ? f2bf(v.y * 2.5f) : (ushort)0;
  r.z = k2 ? f2bf(v.z * 2.5f) : (ushort)0;
  r.w = k3 ? f2bf(v.w * 2.5f) : (ushort)0;
  ((ushort4*)out)[i] = r;
}

// ---------------------------------------------------------------------------
// Fused layer: block = 64 nodes = 4 INDEPENDENT waves of 16 nodes each.
// Per wave (no cross-wave sync anywhere):
//  0) stage: 16 padded degree loads + 2 coalesced 1KB list loads -> wl LDS.
//  1) gather: 4 node-groups of 4; per group 8 row-loads in flight (unroll 2),
//     xor-shfl reduce over quads; quad-0 deposits bf16 rows into As tile.
//  2) MFMA: 8 k-chunks x 8 col-tiles; agg half from As, root half loaded
//     just-in-time (hidden under c<4 MFMAs); B frags from Wpack (L2-hot).
//  3) epilogue: mode=1 ReLU + next dropout -> bf16; mode=0 +bias -> fp32.
// ---------------------------------------------------------------------------
__global__ __launch_bounds__(256, 4) void layer_kernel(const ushort* __restrict__ hd,
                                                       const int* __restrict__ ncnt,
                                                       const ushort* __restrict__ nlist,
                                                       const ushort* __restrict__ Wpack,
                                                       const float* __restrict__ bias,
                                                       const void* __restrict__ mask,
                                                       const int* __restrict__ flags,
                                                       void* __restrict__ outp,
                                                       int mode, int N) {
  __shared__ ushort wl[4][16][CAPN];   // per-wave lists (2KB/wave)
  __shared__ ushort As[4][16][136];    // per-wave A tiles, pad 8 (16B rows)

  const int tid = threadIdx.x;
  const int wave = tid >> 6, lane = tid & 63;
  const int quad = lane >> 4, l16 = lane & 15, co = l16 * 8;
  const int node0 = blockIdx.x * 64 + wave * 16;   // wave's 16 nodes

  // ---- 0) stage ----
  int deg = ncnt[(node0 + l16) * 16];              // node l16's degree
  if (deg > CAPN) deg = CAPN;
  const uint4* lsrc = (const uint4*)(nlist + (size_t)node0 * CAPN);
  uint4 l0 = lsrc[lane];
  uint4 l1 = lsrc[64 + lane];
  const int m32 = flags[1];
  ((uint4*)&wl[wave][0][0])[lane] = l0;
  ((uint4*)&wl[wave][0][0])[64 + lane] = l1;

  // ---- 1) gather: 4 groups of 4 nodes, 8 loads in flight ----
  const ushort* base = hd + co;
#pragma unroll 1
  for (int g = 0; g < 4; ++g) {
    int dc[4];
#pragma unroll
    for (int t = 0; t < 4; ++t) dc[t] = __shfl(deg, g * 4 + t, 64);
    int m = dc[0];
    if (dc[1] > m) m = dc[1];
    if (dc[2] > m) m = dc[2];
    if (dc[3] > m) m = dc[3];

    float ag[4][8];
#pragma unroll
    for (int t = 0; t < 4; ++t)
#pragma unroll
      for (int i = 0; i < 8; ++i) ag[t][i] = 0.f;

    for (int e = quad; e < m; e += 8) {
      int e2 = e + 4;
#pragma unroll
      for (int t = 0; t < 4; ++t) {
        if (e < dc[t]) {
          uint4 v = *(const uint4*)(base + (size_t)wl[wave][g * 4 + t][e] * C128);
          ag[t][0] += bflo(v.x); ag[t][1] += bfhi(v.x);
          ag[t][2] += bflo(v.y); ag[t][3] += bfhi(v.y);
          ag[t][4] += bflo(v.z); ag[t][5] += bfhi(v.z);
          ag[t][6] += bflo(v.w); ag[t][7] += bfhi(v.w);
        }
      }
#pragma unroll
      for (int t = 0; t < 4; ++t) {
        if (e2 < dc[t]) {
          uint4 v = *(const uint4*)(base + (size_t)wl[wave][g * 4 + t][e2] * C128);
          ag[t][0] += bflo(v.x); ag[t][1] += bfhi(v.x);
          ag[t][2] += bflo(v.y); ag[t][3] += bfhi(v.y);
          ag[t][4] += bflo(v.z); ag[t][5] += bfhi(v.z);
          ag[t][6] += bflo(v.w); ag[t][7] += bfhi(v.w);
        }
      }
    }
#pragma unroll
    for (int t = 0; t < 4; ++t) {
#pragma unroll
      for (int i = 0; i < 8; ++i) {
        float v = ag[t][i];
        v += __shfl_xor(v, 16, 64);
        v += __shfl_xor(v, 32, 64);
        ag[t][i] = v;
      }
      if (quad == 0) {
        uint4 p;
        p.x = pack2(ag[t][0], ag[t][1]);
        p.y = pack2(ag[t][2], ag[t][3]);
        p.z = pack2(ag[t][4], ag[t][5]);
        p.w = pack2(ag[t][6], ag[t][7]);
        *(uint4*)&As[wave][g * 4 + t][co] = p;
      }
    }
  }

  // ---- 2) MFMA. Root frags loaded here (hidden under c<4 MFMAs). ----
  int prow = node0 + l16;
  if (prow >= N) prow = N - 1;
  const ushort* hrow = hd + (size_t)prow * C128 + quad * 8;
  s16x8 aroot[4];
#pragma unroll
  for (int c = 0; c < 4; ++c) aroot[c] = *(const s16x8*)(hrow + c * 32);

  f32x4 acc[8];
#pragma unroll
  for (int j = 0; j < 8; ++j) acc[j] = (f32x4)0.f;
  const ushort* wp = Wpack + lane * 8;
#pragma unroll
  for (int c = 0; c < 8; ++c) {
    s16x8 afr;
    if (c < 4) afr = *(const s16x8*)&As[wave][l16][c * 32 + quad * 8];
    else       afr = aroot[c - 4];
#pragma unroll
    for (int nt = 0; nt < 8; ++nt) {
      s16x8 bfr = *(const s16x8*)(wp + (c * 8 + nt) * 512);
      acc[nt] = __builtin_amdgcn_mfma_f32_16x16x32_bf16(afr, bfr, acc[nt], 0, 0, 0);
    }
  }

  // ---- 3) epilogue. C/D layout: col = lane&15, row = quad*4 + reg ----
  if (mode) {
    ushort* ob = (ushort*)outp;
#pragma unroll
    for (int nt = 0; nt < 8; ++nt) {
      float bvv = bias[nt * 16 + l16];
#pragma unroll
      for (int r = 0; r < 4; ++r) {
        int node = node0 + quad * 4 + r;
        if (node >= N) continue;
        size_t idx = (size_t)node * C128 + nt * 16 + l16;
        int keep = m32 ? ((const int*)mask)[idx]
                       : (int)((const unsigned char*)mask)[idx];
        float v = fmaxf(acc[nt][r] + bvv, 0.f);
        ob[idx] = keep ? f2bf(v * 2.5f) : (ushort)0;
      }
    }
  } else {
    float* of = (float*)outp;
#pragma unroll
    for (int nt = 0; nt < 8; ++nt) {
      float bvv = bias[nt * 16 + l16];
#pragma unroll
      for (int r = 0; r < 4; ++r) {
        int node = node0 + quad * 4 + r;
        if (node >= N) continue;
        of[(size_t)node * C128 + nt * 16 + l16] = acc[nt][r] + bvv;
      }
    }
  }
}

// ---------------------------------------------------------------------------
extern "C" void kernel_launch(void* const* d_in, const int* in_sizes, int n_in,
                              void* d_out, int out_size, void* d_ws, size_t ws_size,
                              hipStream_t stream) {
  const float* x      = (const float*)d_in[0];
  const int*   eidx   = (const int*)d_in[1];
  const float* Wrel0  = (const float*)d_in[2];
  const float* Wroot0 = (const float*)d_in[3];
  const float* b0     = (const float*)d_in[4];
  const float* Wrel1  = (const float*)d_in[5];
  const float* Wroot1 = (const float*)d_in[6];
  const float* b1     = (const float*)d_in[7];
  const float* Wrel2  = (const float*)d_in[8];
  const float* Wroot2 = (const float*)d_in[9];
  const float* b2     = (const float*)d_in[10];
  const void*  drop0  = d_in[11];
  const void*  drop1  = d_in[12];
  const void*  drop2  = d_in[13];

  const int N       = in_sizes[0] / C128;
  const int E       = in_sizes[1] / 2;
  const int NC      = N * C128;
  const int nbuck64 = (N + 63) / 64;
  const int Npad    = nbuck64 * 64;
  const int nCnt    = Npad * 16;        // line-padded per-node counters

  char*   ws    = (char*)d_ws;
  int*    flags = (int*)ws;                              // 256 B
  ushort* Wpack = (ushort*)(ws + 256);                   // 3*32768 bf16
  int*    ncnt  = (int*)(Wpack + 3 * 32768);             // nCnt ints
  ushort* nlist = (ushort*)(ncnt + nCnt);                // Npad*CAPN ushort
  ushort* hdA   = (ushort*)(nlist + (size_t)Npad * CAPN);
  ushort* hdB   = hdA + NC;

  const ushort* Wp0 = Wpack;
  const ushort* Wp1 = Wpack + 32768;
  const ushort* Wp2 = Wpack + 2 * 32768;

  int prepT = 3 * 32768 > nCnt ? 3 * 32768 : nCnt;
  prep_kernel<<<(prepT + 255) / 256, 256, 0, stream>>>(
      Wrel0, Wroot0, Wrel1, Wroot1, Wrel2, Wroot2, Wpack,
      eidx, (const int*)drop0, flags, ncnt, nCnt);

  fillb_kernel<<<(E + 255) / 256, 256, 0, stream>>>(eidx, flags, ncnt, nlist, E);

  const int n4 = NC / 4;
  drop_in_kernel<<<(n4 + 255) / 256, 256, 0, stream>>>(x, drop0, flags, hdA, n4);

  // layer 0: hdA -> hdB (relu + drop1 fused)
  layer_kernel<<<nbuck64, 256, 0, stream>>>(hdA, ncnt, nlist, Wp0, b0, drop1,
                                            flags, hdB, 1, N);
  // layer 1: hdB -> hdA (relu + drop2 fused)
  layer_kernel<<<nbuck64, 256, 0, stream>>>(hdB, ncnt, nlist, Wp1, b1, drop2,
                                            flags, hdA, 1, N);
  // layer 2: hdA -> d_out (fp32)
  layer_kernel<<<nbuck64, 256, 0, stream>>>(hdA, ncnt, nlist, Wp2, b2, nullptr,
                                            flags, d_out, 0, N);
}

// Round 2
// 334.603 us; speedup vs baseline: 1.1568x; 1.1568x over previous
//
#include <hip/hip_runtime.h>

// GraphConv x3 on MI355X. R10: R8's high-parallelism block shape (16 nodes,
// 4 waves, grid=3125) fed by R9's once-built node-major edge lists. Bin phase
// replaced by one 512B coalesced list stage per wave; 1 barrier per block.
// Root/bias/mask loads moved AFTER the gather (VGPR pressure peak) and
// __launch_bounds__(256,6) -> 24 waves/CU target. prep+drop_in merged
// (per-wave dtype ballot, flags buffer deleted). 5 dispatches.

#define C128 128
#define CAPN 64     // records per node; mean deg 16, Poisson tail ~1e-18

typedef short s16x8 __attribute__((ext_vector_type(8)));
typedef float f32x4 __attribute__((ext_vector_type(4)));

__device__ __forceinline__ ushort f2bf(float f) {        // RNE fp32->bf16
  unsigned u = __builtin_bit_cast(unsigned, f);
  u = (u + 0x7FFFu + ((u >> 16) & 1u)) >> 16;
  return (ushort)u;
}
__device__ __forceinline__ float bflo(unsigned v) {
  return __builtin_bit_cast(float, v << 16);
}
__device__ __forceinline__ float bfhi(unsigned v) {
  return __builtin_bit_cast(float, v & 0xFFFF0000u);
}
__device__ __forceinline__ unsigned pack2(float lo, float hi) {
  return (unsigned)f2bf(lo) | ((unsigned)f2bf(hi) << 16);
}

// ---------------------------------------------------------------------------
// prep: fused {input dropout fp32->bf16} + {weight pack} + {counter zero}.
// Thread partition: [0,n4) dropout, [n4,n4+96K) pack, rest zero ncnt.
// Mask dtype self-detected per wave via ballot (n4 % 64 == 0 -> uniform).
// Wpack idx = (c*8+nt)*512 + lane*8 + j ->
//   W[o=nt*16+(lane&15)][k=(c&3)*32+(lane>>4)*8+j]; c<4 Wrel, c>=4 Wroot.
// ---------------------------------------------------------------------------
__global__ __launch_bounds__(256) void prep_kernel(const float* __restrict__ Wr0,
                                                   const float* __restrict__ Wt0,
                                                   const float* __restrict__ Wr1,
                                                   const float* __restrict__ Wt1,
                                                   const float* __restrict__ Wr2,
                                                   const float* __restrict__ Wt2,
                                                   ushort* __restrict__ Wpack,
                                                   const float* __restrict__ x,
                                                   const void* __restrict__ mask,
                                                   ushort* __restrict__ hdA,
                                                   int n4,
                                                   int* __restrict__ ncnt,
                                                   int nCnt) {
  int t = blockIdx.x * 256 + threadIdx.x;
  if (t < n4) {
    // per-wave mask dtype detect (wave fully inside this branch: n4 % 64 == 0)
    int lane = threadIdx.x & 63;
    unsigned mv = ((const unsigned*)mask)[lane];
    int m32 = (__ballot(mv > 1u) == 0ull);

    float4 v = ((const float4*)x)[t];
    int k0, k1, k2, k3;
    if (m32) {
      int4 m = ((const int4*)mask)[t];
      k0 = m.x; k1 = m.y; k2 = m.z; k3 = m.w;
    } else {
      uchar4 m = ((const uchar4*)mask)[t];
      k0 = m.x; k1 = m.y; k2 = m.z; k3 = m.w;
    }
    ushort4 r;
    r.x = k0 ? f2bf(v.x * 2.5f) : (ushort)0;
    r.y = k1 ? f2bf(v.y * 2.5f) : (ushort)0;
    r.z = k2 ? f2bf(v.z * 2.5f) : (ushort)0;
    r.w = k3 ? f2bf(v.w * 2.5f) : (ushort)0;
    ((ushort4*)hdA)[t] = r;
    return;
  }
  int u = t - n4;
  if (u < 3 * 32768) {
    int L = u >> 15;
    int r = u & 32767;
    int c = r >> 12;
    int nt = (r >> 9) & 7;
    int lane = (r >> 3) & 63;
    int j = r & 7;
    int o = nt * 16 + (lane & 15);
    int k = (c & 3) * 32 + (lane >> 4) * 8 + j;
    const float* src;
    if (L == 0)      src = (c < 4) ? Wr0 : Wt0;
    else if (L == 1) src = (c < 4) ? Wr1 : Wt1;
    else             src = (c < 4) ? Wr2 : Wt2;
    Wpack[u] = f2bf(src[o * C128 + k]);
    return;
  }
  int z = u - 3 * 32768;
  if (z < nCnt) ncnt[z] = 0;
}

// ---------------------------------------------------------------------------
// fillb: edge -> per-node list, node-major (ushort src, N<65536).
// Counter line-padded (x16 ints). Edge dtype self-detected per wave.
// ---------------------------------------------------------------------------
__global__ __launch_bounds__(256) void fillb_kernel(const int* __restrict__ eidx,
                                                    int* __restrict__ ncnt,
                                                    ushort* __restrict__ nlist,
                                                    int E) {
  int lane = threadIdx.x & 63;
  unsigned long long be = __ballot(eidx[2 * lane + 1] != 0);
  int e64 = (be == 0ull);   // 1 = edges are int64
  int e = blockIdx.x * 256 + threadIdx.x;
  if (e >= E) return;
  int src, dst;
  if (e64) { src = eidx[2 * e]; dst = eidx[2 * E + 2 * e]; }
  else     { src = eidx[e];     dst = eidx[E + e]; }
  int pos = atomicAdd(&ncnt[dst * 16], 1);
  if (pos < CAPN) nlist[(size_t)dst * CAPN + pos] = (ushort)src;
}

// ---------------------------------------------------------------------------
// Fused layer: block = 16 nodes, 4 waves.
//  0) stage: one coalesced 512B list load per wave (wave w -> nodes 4w..4w+3)
//     + 16 line-padded degree loads; wave-private LDS, no barrier needed.
//  1) gather: 4 nodes simultaneously, unroll 2 -> 8 independent 1KB row
//     loads in flight; xor-shfl reduce over quads; quad-0 deposits bf16 node
//     rows into 16x136 LDS tile. ONE barrier.
//  2) MFMA: wave w -> col tiles {2w,2w+1}; agg half from LDS, root half
//     loaded here (post-gather: keeps gather-phase VGPR pressure low);
//     B frags from Wpack (L2-hot).
//  3) epilogue: mode=1 ReLU + next dropout -> bf16; mode=0 +bias -> fp32.
// ---------------------------------------------------------------------------
__global__ __launch_bounds__(256, 6) void layer_kernel(const ushort* __restrict__ hd,
                                                       const int* __restrict__ ncnt,
                                                       const ushort* __restrict__ nlist,
                                                       const ushort* __restrict__ Wpack,
                                                       const float* __restrict__ bias,
                                                       const void* __restrict__ mask,
                                                       void* __restrict__ outp,
                                                       int mode, int N) {
  __shared__ ushort wl[16][CAPN];   // per-wave 4-row slices (512B/wave)
  __shared__ ushort As[16][136];    // 16 node rows, pad 8 (16B-aligned rows)

  const int tid = threadIdx.x;
  const int wave = tid >> 6, lane = tid & 63;
  const int quad = lane >> 4, l16 = lane & 15, co = l16 * 8;
  const int node0 = blockIdx.x * 16;
  const int nb0 = wave * 4;

  // mask dtype detect (wave-uniform ballot; cheap, L1/L2-hot broadcast)
  int m32 = 0;
  if (mode) {
    unsigned mv = ((const unsigned*)mask)[lane];
    m32 = (__ballot(mv > 1u) == 0ull);
  }

  // ---- 0) stage: degrees + this wave's 4 node lists ----
  int deg16 = ncnt[(node0 + l16) * 16];
  if (deg16 > CAPN) deg16 = CAPN;
  ((uint2*)&wl[nb0][0])[lane] =
      ((const uint2*)(nlist + (size_t)(node0 + nb0) * CAPN))[lane];

  int dc[4];
#pragma unroll
  for (int t = 0; t < 4; ++t) dc[t] = __shfl(deg16, nb0 + t, 64);
  int m = dc[0];
  if (dc[1] > m) m = dc[1];
  if (dc[2] > m) m = dc[2];
  if (dc[3] > m) m = dc[3];

  // ---- 1) gather: 4 nodes simultaneously, unroll 2 ----
  const ushort* base = hd + co;
  float ag[4][8];
#pragma unroll
  for (int t = 0; t < 4; ++t)
#pragma unroll
    for (int i = 0; i < 8; ++i) ag[t][i] = 0.f;

  for (int e = quad; e < m; e += 8) {
    int e2 = e + 4;
#pragma unroll
    for (int t = 0; t < 4; ++t) {
      if (e < dc[t]) {
        uint4 v = *(const uint4*)(base + (size_t)wl[nb0 + t][e] * C128);
        ag[t][0] += bflo(v.x); ag[t][1] += bfhi(v.x);
        ag[t][2] += bflo(v.y); ag[t][3] += bfhi(v.y);
        ag[t][4] += bflo(v.z); ag[t][5] += bfhi(v.z);
        ag[t][6] += bflo(v.w); ag[t][7] += bfhi(v.w);
      }
    }
#pragma unroll
    for (int t = 0; t < 4; ++t) {
      if (e2 < dc[t]) {
        uint4 v = *(const uint4*)(base + (size_t)wl[nb0 + t][e2] * C128);
        ag[t][0] += bflo(v.x); ag[t][1] += bfhi(v.x);
        ag[t][2] += bflo(v.y); ag[t][3] += bfhi(v.y);
        ag[t][4] += bflo(v.z); ag[t][5] += bfhi(v.z);
        ag[t][6] += bflo(v.w); ag[t][7] += bfhi(v.w);
      }
    }
  }
#pragma unroll
  for (int t = 0; t < 4; ++t) {
#pragma unroll
    for (int i = 0; i < 8; ++i) {
      float v = ag[t][i];
      v += __shfl_xor(v, 16, 64);
      v += __shfl_xor(v, 32, 64);
      ag[t][i] = v;
    }
    if (quad == 0) {
      uint4 p;
      p.x = pack2(ag[t][0], ag[t][1]);
      p.y = pack2(ag[t][2], ag[t][3]);
      p.z = pack2(ag[t][4], ag[t][5]);
      p.w = pack2(ag[t][6], ag[t][7]);
      *(uint4*)&As[nb0 + t][co] = p;
    }
  }
  __syncthreads();

  // ---- 2) MFMA. Root frags loaded here (post-gather, TLP hides latency) ----
  int prow = node0 + l16;
  if (prow >= N) prow = N - 1;
  const ushort* hrow = hd + (size_t)prow * C128 + quad * 8;
  s16x8 aroot[4];
#pragma unroll
  for (int c = 0; c < 4; ++c) aroot[c] = *(const s16x8*)(hrow + c * 32);

  f32x4 acc[2];
  acc[0] = (f32x4)0.f;
  acc[1] = (f32x4)0.f;
  const ushort* wp = Wpack + lane * 8;
#pragma unroll
  for (int c = 0; c < 8; ++c) {
    s16x8 afr;
    if (c < 4) afr = *(const s16x8*)&As[l16][c * 32 + quad * 8];
    else       afr = aroot[c - 4];
#pragma unroll
    for (int j = 0; j < 2; ++j) {
      int nt = wave * 2 + j;
      s16x8 bfr = *(const s16x8*)(wp + (c * 8 + nt) * 512);
      acc[j] = __builtin_amdgcn_mfma_f32_16x16x32_bf16(afr, bfr, acc[j], 0, 0, 0);
    }
  }

  // ---- 3) epilogue. C/D layout: col = lane&15, row = quad*4 + reg ----
  if (mode) {
    ushort* ob = (ushort*)outp;
#pragma unroll
    for (int j = 0; j < 2; ++j) {
      int o = (wave * 2 + j) * 16 + l16;
      float bvv = bias[o];
#pragma unroll
      for (int r = 0; r < 4; ++r) {
        int node = node0 + quad * 4 + r;
        if (node >= N) continue;
        size_t idx = (size_t)node * C128 + o;
        int keep = m32 ? ((const int*)mask)[idx]
                       : (int)((const unsigned char*)mask)[idx];
        float v = fmaxf(acc[j][r] + bvv, 0.f);
        ob[idx] = keep ? f2bf(v * 2.5f) : (ushort)0;
      }
    }
  } else {
    float* of = (float*)outp;
#pragma unroll
    for (int j = 0; j < 2; ++j) {
      int o = (wave * 2 + j) * 16 + l16;
      float bvv = bias[o];
#pragma unroll
      for (int r = 0; r < 4; ++r) {
        int node = node0 + quad * 4 + r;
        if (node >= N) continue;
        of[(size_t)node * C128 + o] = acc[j][r] + bvv;
      }
    }
  }
}

// ---------------------------------------------------------------------------
extern "C" void kernel_launch(void* const* d_in, const int* in_sizes, int n_in,
                              void* d_out, int out_size, void* d_ws, size_t ws_size,
                              hipStream_t stream) {
  const float* x      = (const float*)d_in[0];
  const int*   eidx   = (const int*)d_in[1];
  const float* Wrel0  = (const float*)d_in[2];
  const float* Wroot0 = (const float*)d_in[3];
  const float* b0     = (const float*)d_in[4];
  const float* Wrel1  = (const float*)d_in[5];
  const float* Wroot1 = (const float*)d_in[6];
  const float* b1     = (const float*)d_in[7];
  const float* Wrel2  = (const float*)d_in[8];
  const float* Wroot2 = (const float*)d_in[9];
  const float* b2     = (const float*)d_in[10];
  const void*  drop0  = d_in[11];
  const void*  drop1  = d_in[12];
  const void*  drop2  = d_in[13];

  const int N       = in_sizes[0] / C128;
  const int E       = in_sizes[1] / 2;
  const int NC      = N * C128;
  const int nbuck16 = (N + 15) / 16;
  const int Npad    = nbuck16 * 16;
  const int nCnt    = Npad * 16;        // line-padded per-node counters

  char*   ws    = (char*)d_ws;
  ushort* Wpack = (ushort*)ws;                           // 3*32768 bf16
  int*    ncnt  = (int*)(Wpack + 3 * 32768);             // nCnt ints
  ushort* nlist = (ushort*)(ncnt + nCnt);                // Npad*CAPN ushort
  ushort* hdA   = (ushort*)(nlist + (size_t)Npad * CAPN);
  ushort* hdB   = hdA + NC;

  const ushort* Wp0 = Wpack;
  const ushort* Wp1 = Wpack + 32768;
  const ushort* Wp2 = Wpack + 2 * 32768;

  const int n4    = NC / 4;
  const int prepT = n4 + 3 * 32768 + nCnt;
  prep_kernel<<<(prepT + 255) / 256, 256, 0, stream>>>(
      Wrel0, Wroot0, Wrel1, Wroot1, Wrel2, Wroot2, Wpack,
      x, drop0, hdA, n4, ncnt, nCnt);

  fillb_kernel<<<(E + 255) / 256, 256, 0, stream>>>(eidx, ncnt, nlist, E);

  // layer 0: hdA -> hdB (relu + drop1 fused)
  layer_kernel<<<nbuck16, 256, 0, stream>>>(hdA, ncnt, nlist, Wp0, b0, drop1,
                                            hdB, 1, N);
  // layer 1: hdB -> hdA (relu + drop2 fused)
  layer_kernel<<<nbuck16, 256, 0, stream>>>(hdB, ncnt, nlist, Wp1, b1, drop2,
                                            hdA, 1, N);
  // layer 2: hdA -> d_out (fp32)
  layer_kernel<<<nbuck16, 256, 0, stream>>>(hdA, ncnt, nlist, Wp2, b2, nullptr,
                                            d_out, 0, N);
}